// Round 3
// baseline (7826.623 us; speedup 1.0000x reference)
//
#include <hip/hip_runtime.h>
#include <stdint.h>

#define B 64
#define T 512
#define D 256

// ---------------------------------------------------------------- K_prep: weight transposes (k-major)
__global__ void k_prep(const float* __restrict__ W1, const float* __restrict__ Wr,
                       const float* __restrict__ Wg,
                       float* __restrict__ W1t, float* __restrict__ Wrt, float* __restrict__ Wgt)
{
  int64_t stride = (int64_t)gridDim.x * blockDim.x;
  for (int64_t i = (int64_t)blockIdx.x * blockDim.x + threadIdx.x;
       i < 262144 + 65536 + 65536; i += stride) {
    if (i < 262144) {
      int k = (int)(i >> 8), a = (int)(i & 255);
      W1t[i] = W1[(int64_t)a * 1024 + k];          // W1t[k][a]
    } else if (i < 262144 + 65536) {
      int j = (int)(i - 262144); int k = j >> 8, a = j & 255;
      Wrt[j] = Wr[a * 256 + k];                    // Wrt[k][i]
    } else {
      int j = (int)(i - 262144 - 65536); int k = j >> 8, a = j & 255;
      Wgt[j] = Wg[a * 256 + k];                    // Wgt[k][i]
    }
  }
}

// ---------------------------------------------------------------- K1: attention logits, f32 VALU
__global__ __launch_bounds__(256) void k_attn_f32(
    const float* __restrict__ facts, const float* __restrict__ queries,
    const float* __restrict__ m_old, const float* __restrict__ W1t,
    const float* __restrict__ W1_b, const float* __restrict__ W2_w,
    const float* __restrict__ W2_b, float* __restrict__ Zlog)
{
  const int b = blockIdx.y;
  const int t0 = blockIdx.x * 32;
  const int tid = threadIdx.x;
  const int u = tid & 31;
  const int rg = tid >> 5;

  __shared__ float q_s[256], m_s[256];
  __shared__ float zsr[32][33];
  __shared__ float zpart[8][4];

  q_s[tid] = queries[b * 256 + tid];
  m_s[tid] = m_old[b * 256 + tid];

  float acc[4][8];
  #pragma unroll
  for (int i = 0; i < 4; ++i)
    #pragma unroll
    for (int j = 0; j < 8; ++j) acc[i][j] = 0.f;

  for (int kc = 0; kc < 32; ++kc) {
    __syncthreads();
    const int s = kc >> 3;
    const int fbase = (kc & 7) * 32;
    for (int idx = tid; idx < 1024; idx += 256) {
      int kk = idx & 31, r = idx >> 5;
      float fv = facts[((int64_t)(b * T) + t0 + r) * D + fbase + kk];
      float q = q_s[fbase + kk], mm = m_s[fbase + kk];
      float z = (s == 0) ? fv * q : (s == 1) ? fv * mm
              : (s == 2) ? fabsf(fv - q) : fabsf(fv - mm);
      zsr[r][kk] = z;
    }
    __syncthreads();
    const float* wbase = W1t + (int64_t)(kc * 32) * 256 + u * 8;
    #pragma unroll 4
    for (int kk = 0; kk < 32; ++kk) {
      float4 w0 = *(const float4*)(wbase + kk * 256);
      float4 w1 = *(const float4*)(wbase + kk * 256 + 4);
      float wv[8] = {w0.x, w0.y, w0.z, w0.w, w1.x, w1.y, w1.z, w1.w};
      float zv[4] = {zsr[rg * 4 + 0][kk], zsr[rg * 4 + 1][kk],
                     zsr[rg * 4 + 2][kk], zsr[rg * 4 + 3][kk]};
      #pragma unroll
      for (int i = 0; i < 4; ++i)
        #pragma unroll
        for (int j = 0; j < 8; ++j) acc[i][j] += zv[i] * wv[j];
    }
  }

  float b1[8], w2[8];
  #pragma unroll
  for (int j = 0; j < 8; ++j) { b1[j] = W1_b[u * 8 + j]; w2[j] = W2_w[u * 8 + j]; }
  #pragma unroll
  for (int i = 0; i < 4; ++i) {
    float v = 0.f;
    #pragma unroll
    for (int j = 0; j < 8; ++j) v += tanhf(acc[i][j] + b1[j]) * w2[j];
    v += __shfl_xor(v, 1, 64);
    v += __shfl_xor(v, 2, 64);
    v += __shfl_xor(v, 4, 64);
    v += __shfl_xor(v, 8, 64);
    v += __shfl_xor(v, 16, 64);
    if (u == 0) zpart[rg][i] = v;
  }
  __syncthreads();
  if (tid < 32)
    Zlog[b * T + t0 + tid] = zpart[tid >> 2][tid & 3] + W2_b[0];
}

// ---------------------------------------------------------------- K2: fact projections, f32 VALU
__global__ __launch_bounds__(256) void k_factproj_f32(
    const float* __restrict__ facts, const float* __restrict__ Wrt,
    const float* __restrict__ Wgt, const float* __restrict__ Ur_b,
    float* __restrict__ Fr, float* __restrict__ Fg)
{
  const int b = blockIdx.y;
  const int t0 = blockIdx.x * 32;
  const int tid = threadIdx.x;
  const int u = tid & 31;
  const int rg = tid >> 5;

  __shared__ float fsr[32][33];

  float accR[4][8], accG[4][8];
  #pragma unroll
  for (int i = 0; i < 4; ++i)
    #pragma unroll
    for (int j = 0; j < 8; ++j) { accR[i][j] = 0.f; accG[i][j] = 0.f; }

  for (int kc = 0; kc < 8; ++kc) {
    __syncthreads();
    for (int idx = tid; idx < 1024; idx += 256) {
      int kk = idx & 31, r = idx >> 5;
      fsr[r][kk] = facts[((int64_t)(b * T) + t0 + r) * D + kc * 32 + kk];
    }
    __syncthreads();
    const float* wrb = Wrt + (int64_t)(kc * 32) * 256 + u * 8;
    const float* wgb = Wgt + (int64_t)(kc * 32) * 256 + u * 8;
    #pragma unroll 2
    for (int kk = 0; kk < 32; ++kk) {
      float4 r0 = *(const float4*)(wrb + kk * 256);
      float4 r1 = *(const float4*)(wrb + kk * 256 + 4);
      float4 g0 = *(const float4*)(wgb + kk * 256);
      float4 g1 = *(const float4*)(wgb + kk * 256 + 4);
      float wr[8] = {r0.x, r0.y, r0.z, r0.w, r1.x, r1.y, r1.z, r1.w};
      float wg[8] = {g0.x, g0.y, g0.z, g0.w, g1.x, g1.y, g1.z, g1.w};
      float zv[4] = {fsr[rg * 4 + 0][kk], fsr[rg * 4 + 1][kk],
                     fsr[rg * 4 + 2][kk], fsr[rg * 4 + 3][kk]};
      #pragma unroll
      for (int i = 0; i < 4; ++i)
        #pragma unroll
        for (int j = 0; j < 8; ++j) {
          accR[i][j] += zv[i] * wr[j];
          accG[i][j] += zv[i] * wg[j];
        }
    }
  }

  float urb[8];
  #pragma unroll
  for (int j = 0; j < 8; ++j) urb[j] = Ur_b[u * 8 + j];
  #pragma unroll
  for (int i = 0; i < 4; ++i) {
    int64_t off = ((int64_t)(b * T) + t0 + rg * 4 + i) * D + u * 8;
    float4 o0 = {accR[i][0] + urb[0], accR[i][1] + urb[1], accR[i][2] + urb[2], accR[i][3] + urb[3]};
    float4 o1 = {accR[i][4] + urb[4], accR[i][5] + urb[5], accR[i][6] + urb[6], accR[i][7] + urb[7]};
    float4 p0 = {accG[i][0], accG[i][1], accG[i][2], accG[i][3]};
    float4 p1 = {accG[i][4], accG[i][5], accG[i][6], accG[i][7]};
    *(float4*)(Fr + off) = o0;
    *(float4*)(Fr + off + 4) = o1;
    *(float4*)(Fg + off) = p0;
    *(float4*)(Fg + off + 4) = p1;
  }
}

// ---------------------------------------------------------------- K3: masked softmax, 1 wave per batch
__global__ void k_softmax2(const float* __restrict__ Zlog, const int* __restrict__ num_facts,
                           float* __restrict__ g)
{
  const int b = blockIdx.x;
  const int lane = threadIdx.x;       // 64 threads
  const int nf = num_facts[b];
  float v[8];
  float mx = -INFINITY;
  #pragma unroll
  for (int j = 0; j < 8; ++j) {
    int t = j * 64 + lane;
    float z = Zlog[b * T + t];
    v[j] = (t < nf) ? z : -INFINITY;
    mx = fmaxf(mx, v[j]);
  }
  #pragma unroll
  for (int s = 1; s < 64; s <<= 1) mx = fmaxf(mx, __shfl_xor(mx, s, 64));
  float e[8];
  float sum = 0.f;
  #pragma unroll
  for (int j = 0; j < 8; ++j) {
    int t = j * 64 + lane;
    e[j] = (t < nf) ? __expf(v[j] - mx) : 0.f;
    sum += e[j];
  }
  #pragma unroll
  for (int s = 1; s < 64; s <<= 1) sum += __shfl_xor(sum, s, 64);
  float inv = 1.f / sum;
  #pragma unroll
  for (int j = 0; j < 8; ++j)
    g[b * T + j * 64 + lane] = e[j] * inv;
}

// ---------------------------------------------------------------- K4: AGRU scan, pure f32, no cleverness
// thread i computes BOTH r_i and h_i; h lives in LDS (f32); weights streamed from L2.
__global__ __launch_bounds__(256) void k_scan_f32(
    const float* __restrict__ Fr, const float* __restrict__ Fg, const float* __restrict__ g,
    const int* __restrict__ num_facts, const float* __restrict__ Ur_w,
    const float* __restrict__ Ug_w, const float* __restrict__ Ug_b,
    const float* __restrict__ m_old, float* __restrict__ c_out)
{
  const int b = blockIdx.x;
  const int i = threadIdx.x;
  const int nf = num_facts[b];

  __shared__ __align__(16) float h_s[256];

  const float* __restrict__ urow = Ur_w + (int64_t)i * 256;
  const float* __restrict__ grow = Ug_w + (int64_t)i * 256;
  const float ugb = Ug_b[i];

  h_s[i] = m_old[b * 256 + i];
  __syncthreads();

  for (int t = 0; t < nf; ++t) {
    const int64_t fo = ((int64_t)(b * T) + t) * D + i;
    float fr = Fr[fo];                 // already contains Ur_b
    float fg = Fg[fo];
    float gt = g[b * T + t];

    float dr = 0.f;
    #pragma unroll 8
    for (int k = 0; k < 256; k += 4) {
      float4 w = *(const float4*)(urow + k);
      float4 h4 = *(const float4*)(h_s + k);
      dr += w.x * h4.x + w.y * h4.y + w.z * h4.z + w.w * h4.w;
    }
    float r = 1.f / (1.f + __expf(-(fr + dr)));

    float dg = 0.f;
    #pragma unroll 8
    for (int k = 0; k < 256; k += 4) {
      float4 w = *(const float4*)(grow + k);
      float4 h4 = *(const float4*)(h_s + k);
      dg += w.x * h4.x + w.y * h4.y + w.z * h4.z + w.w * h4.w;
    }
    float ht = tanhf(fg + r * (dg + ugb));
    float hn = gt * ht + (1.f - gt) * h_s[i];

    __syncthreads();
    h_s[i] = hn;
    __syncthreads();
  }
  c_out[b * 256 + i] = h_s[i];
}

// ---------------------------------------------------------------- K5: m_new = relu(cat @ Wt^T + bt)
__global__ __launch_bounds__(256) void k_final2(
    const float* __restrict__ m_old, const float* __restrict__ c_ws,
    const float* __restrict__ queries, const float* __restrict__ Wt_w,
    const float* __restrict__ Wt_b, float* __restrict__ out)
{
  const int b = blockIdx.x;
  const int tid = threadIdx.x;
  __shared__ __align__(16) float cat_s[768];
  for (int e = tid; e < 768; e += 256) {
    float v = (e < 256) ? m_old[b * 256 + e]
            : (e < 512) ? c_ws[b * 256 + (e - 256)]
                        : queries[b * 256 + (e - 512)];
    cat_s[e] = v;
  }
  __syncthreads();
  const float* wrow = Wt_w + (int64_t)tid * 768;
  float acc = 0.f;
  #pragma unroll 8
  for (int k = 0; k < 768; k += 4) {
    float4 w = *(const float4*)(wrow + k);
    float4 c4 = *(const float4*)(cat_s + k);
    acc += w.x * c4.x + w.y * c4.y + w.z * c4.z + w.w * c4.w;
  }
  out[b * 256 + tid] = fmaxf(acc + Wt_b[tid], 0.f);
}

// ----------------------------------------------------------------
extern "C" void kernel_launch(void* const* d_in, const int* in_sizes, int n_in,
                              void* d_out, int out_size, void* d_ws, size_t ws_size,
                              hipStream_t stream)
{
  const float* queries   = (const float*)d_in[0];
  const float* facts     = (const float*)d_in[1];
  const int*   num_facts = (const int*)d_in[2];
  const float* m_old     = (const float*)d_in[3];
  const float* W1_w = (const float*)d_in[4];
  const float* W1_b = (const float*)d_in[5];
  const float* W2_w = (const float*)d_in[6];
  const float* W2_b = (const float*)d_in[7];
  const float* Wr_w = (const float*)d_in[8];
  const float* Ur_w = (const float*)d_in[9];
  const float* Ur_b = (const float*)d_in[10];
  const float* Wg_w = (const float*)d_in[11];
  const float* Ug_w = (const float*)d_in[12];
  const float* Ug_b = (const float*)d_in[13];
  const float* Wt_w = (const float*)d_in[14];
  const float* Wt_b = (const float*)d_in[15];
  float* out = (float*)d_out;

  char* p = (char*)d_ws;
  auto alloc = [&](size_t bytes) { char* r = p; p += (bytes + 255) & ~(size_t)255; return r; };
  float* W1t  = (float*)alloc((size_t)262144 * 4);
  float* Wrt  = (float*)alloc((size_t)65536 * 4);
  float* Wgt  = (float*)alloc((size_t)65536 * 4);
  float* Zlog = (float*)alloc((size_t)B * T * 4);
  float* g    = (float*)alloc((size_t)B * T * 4);
  float* Fr   = (float*)alloc((size_t)B * T * D * 4);
  float* Fg   = (float*)alloc((size_t)B * T * D * 4);
  float* c_ws = (float*)alloc((size_t)B * D * 4);

  k_prep<<<dim3(512), dim3(256), 0, stream>>>(W1_w, Wr_w, Wg_w, W1t, Wrt, Wgt);
  k_attn_f32<<<dim3(16, 64), dim3(256), 0, stream>>>(facts, queries, m_old, W1t, W1_b, W2_w, W2_b, Zlog);
  k_factproj_f32<<<dim3(16, 64), dim3(256), 0, stream>>>(facts, Wrt, Wgt, Ur_b, Fr, Fg);
  k_softmax2<<<dim3(64), dim3(64), 0, stream>>>(Zlog, num_facts, g);
  k_scan_f32<<<dim3(64), dim3(256), 0, stream>>>(Fr, Fg, g, num_facts, Ur_w, Ug_w, Ug_b, m_old, c_ws);
  k_final2<<<dim3(64), dim3(256), 0, stream>>>(m_old, c_ws, queries, Wt_w, Wt_b, out);
}

// Round 4
// 1024.547 us; speedup vs baseline: 7.6391x; 7.6391x over previous
//
#include <hip/hip_runtime.h>
#include <hip/hip_fp16.h>
#include <stdint.h>

#define B 64
#define T 512
#define D 256

typedef _Float16 f16;
typedef __attribute__((ext_vector_type(2))) _Float16 f16x2;
typedef __attribute__((ext_vector_type(4))) unsigned int u32x4;

static __device__ __forceinline__ float dot2f(f16x2 a, f16x2 b, float c) {
  return __builtin_amdgcn_fdot2(a, b, c, false);
}
static __device__ __forceinline__ f16x2 as_h2(unsigned int u) {
  return __builtin_bit_cast(f16x2, u);
}

// ---------------------------------------------------------------- K_prep: weight transposes (k-major)
__global__ void k_prep(const float* __restrict__ W1, const float* __restrict__ Wr,
                       const float* __restrict__ Wg,
                       float* __restrict__ W1t, float* __restrict__ Wrt, float* __restrict__ Wgt)
{
  int64_t stride = (int64_t)gridDim.x * blockDim.x;
  for (int64_t i = (int64_t)blockIdx.x * blockDim.x + threadIdx.x;
       i < 262144 + 65536 + 65536; i += stride) {
    if (i < 262144) {
      int k = (int)(i >> 8), a = (int)(i & 255);
      W1t[i] = W1[(int64_t)a * 1024 + k];          // W1t[k][a]
    } else if (i < 262144 + 65536) {
      int j = (int)(i - 262144); int k = j >> 8, a = j & 255;
      Wrt[j] = Wr[a * 256 + k];                    // Wrt[k][i]
    } else {
      int j = (int)(i - 262144 - 65536); int k = j >> 8, a = j & 255;
      Wgt[j] = Wg[a * 256 + k];                    // Wgt[k][i]
    }
  }
}

// ---------------------------------------------------------------- K1: attention logits, f32 VALU
__global__ __launch_bounds__(256) void k_attn_f32(
    const float* __restrict__ facts, const float* __restrict__ queries,
    const float* __restrict__ m_old, const float* __restrict__ W1t,
    const float* __restrict__ W1_b, const float* __restrict__ W2_w,
    const float* __restrict__ W2_b, float* __restrict__ Zlog)
{
  const int b = blockIdx.y;
  const int t0 = blockIdx.x * 32;
  const int tid = threadIdx.x;
  const int u = tid & 31;
  const int rg = tid >> 5;

  __shared__ float q_s[256], m_s[256];
  __shared__ float zsr[32][33];
  __shared__ float zpart[8][4];

  q_s[tid] = queries[b * 256 + tid];
  m_s[tid] = m_old[b * 256 + tid];

  float acc[4][8];
  #pragma unroll
  for (int i = 0; i < 4; ++i)
    #pragma unroll
    for (int j = 0; j < 8; ++j) acc[i][j] = 0.f;

  for (int kc = 0; kc < 32; ++kc) {
    __syncthreads();
    const int s = kc >> 3;
    const int fbase = (kc & 7) * 32;
    for (int idx = tid; idx < 1024; idx += 256) {
      int kk = idx & 31, r = idx >> 5;
      float fv = facts[((int64_t)(b * T) + t0 + r) * D + fbase + kk];
      float q = q_s[fbase + kk], mm = m_s[fbase + kk];
      float z = (s == 0) ? fv * q : (s == 1) ? fv * mm
              : (s == 2) ? fabsf(fv - q) : fabsf(fv - mm);
      zsr[r][kk] = z;
    }
    __syncthreads();
    const float* wbase = W1t + (int64_t)(kc * 32) * 256 + u * 8;
    #pragma unroll 4
    for (int kk = 0; kk < 32; ++kk) {
      float4 w0 = *(const float4*)(wbase + kk * 256);
      float4 w1 = *(const float4*)(wbase + kk * 256 + 4);
      float wv[8] = {w0.x, w0.y, w0.z, w0.w, w1.x, w1.y, w1.z, w1.w};
      float zv[4] = {zsr[rg * 4 + 0][kk], zsr[rg * 4 + 1][kk],
                     zsr[rg * 4 + 2][kk], zsr[rg * 4 + 3][kk]};
      #pragma unroll
      for (int i = 0; i < 4; ++i)
        #pragma unroll
        for (int j = 0; j < 8; ++j) acc[i][j] += zv[i] * wv[j];
    }
  }

  float b1[8], w2[8];
  #pragma unroll
  for (int j = 0; j < 8; ++j) { b1[j] = W1_b[u * 8 + j]; w2[j] = W2_w[u * 8 + j]; }
  #pragma unroll
  for (int i = 0; i < 4; ++i) {
    float v = 0.f;
    #pragma unroll
    for (int j = 0; j < 8; ++j) v += tanhf(acc[i][j] + b1[j]) * w2[j];
    v += __shfl_xor(v, 1, 64);
    v += __shfl_xor(v, 2, 64);
    v += __shfl_xor(v, 4, 64);
    v += __shfl_xor(v, 8, 64);
    v += __shfl_xor(v, 16, 64);
    if (u == 0) zpart[rg][i] = v;
  }
  __syncthreads();
  if (tid < 32)
    Zlog[b * T + t0 + tid] = zpart[tid >> 2][tid & 3] + W2_b[0];
}

// ---------------------------------------------------------------- K2: fact projections, f32 VALU
__global__ __launch_bounds__(256) void k_factproj_f32(
    const float* __restrict__ facts, const float* __restrict__ Wrt,
    const float* __restrict__ Wgt, const float* __restrict__ Ur_b,
    float* __restrict__ Fr, float* __restrict__ Fg)
{
  const int b = blockIdx.y;
  const int t0 = blockIdx.x * 32;
  const int tid = threadIdx.x;
  const int u = tid & 31;
  const int rg = tid >> 5;

  __shared__ float fsr[32][33];

  float accR[4][8], accG[4][8];
  #pragma unroll
  for (int i = 0; i < 4; ++i)
    #pragma unroll
    for (int j = 0; j < 8; ++j) { accR[i][j] = 0.f; accG[i][j] = 0.f; }

  for (int kc = 0; kc < 8; ++kc) {
    __syncthreads();
    for (int idx = tid; idx < 1024; idx += 256) {
      int kk = idx & 31, r = idx >> 5;
      fsr[r][kk] = facts[((int64_t)(b * T) + t0 + r) * D + kc * 32 + kk];
    }
    __syncthreads();
    const float* wrb = Wrt + (int64_t)(kc * 32) * 256 + u * 8;
    const float* wgb = Wgt + (int64_t)(kc * 32) * 256 + u * 8;
    #pragma unroll 2
    for (int kk = 0; kk < 32; ++kk) {
      float4 r0 = *(const float4*)(wrb + kk * 256);
      float4 r1 = *(const float4*)(wrb + kk * 256 + 4);
      float4 g0 = *(const float4*)(wgb + kk * 256);
      float4 g1 = *(const float4*)(wgb + kk * 256 + 4);
      float wr[8] = {r0.x, r0.y, r0.z, r0.w, r1.x, r1.y, r1.z, r1.w};
      float wg[8] = {g0.x, g0.y, g0.z, g0.w, g1.x, g1.y, g1.z, g1.w};
      float zv[4] = {fsr[rg * 4 + 0][kk], fsr[rg * 4 + 1][kk],
                     fsr[rg * 4 + 2][kk], fsr[rg * 4 + 3][kk]};
      #pragma unroll
      for (int i = 0; i < 4; ++i)
        #pragma unroll
        for (int j = 0; j < 8; ++j) {
          accR[i][j] += zv[i] * wr[j];
          accG[i][j] += zv[i] * wg[j];
        }
    }
  }

  float urb[8];
  #pragma unroll
  for (int j = 0; j < 8; ++j) urb[j] = Ur_b[u * 8 + j];
  #pragma unroll
  for (int i = 0; i < 4; ++i) {
    int64_t off = ((int64_t)(b * T) + t0 + rg * 4 + i) * D + u * 8;
    float4 o0 = {accR[i][0] + urb[0], accR[i][1] + urb[1], accR[i][2] + urb[2], accR[i][3] + urb[3]};
    float4 o1 = {accR[i][4] + urb[4], accR[i][5] + urb[5], accR[i][6] + urb[6], accR[i][7] + urb[7]};
    float4 p0 = {accG[i][0], accG[i][1], accG[i][2], accG[i][3]};
    float4 p1 = {accG[i][4], accG[i][5], accG[i][6], accG[i][7]};
    *(float4*)(Fr + off) = o0;
    *(float4*)(Fr + off + 4) = o1;
    *(float4*)(Fg + off) = p0;
    *(float4*)(Fg + off + 4) = p1;
  }
}

// ---------------------------------------------------------------- K3: masked softmax, 1 wave per batch
__global__ void k_softmax2(const float* __restrict__ Zlog, const int* __restrict__ num_facts,
                           float* __restrict__ g)
{
  const int b = blockIdx.x;
  const int lane = threadIdx.x;       // 64 threads
  const int nf = num_facts[b];
  float v[8];
  float mx = -INFINITY;
  #pragma unroll
  for (int j = 0; j < 8; ++j) {
    int t = j * 64 + lane;
    float z = Zlog[b * T + t];
    v[j] = (t < nf) ? z : -INFINITY;
    mx = fmaxf(mx, v[j]);
  }
  #pragma unroll
  for (int s = 1; s < 64; s <<= 1) mx = fmaxf(mx, __shfl_xor(mx, s, 64));
  float e[8];
  float sum = 0.f;
  #pragma unroll
  for (int j = 0; j < 8; ++j) {
    int t = j * 64 + lane;
    e[j] = (t < nf) ? __expf(v[j] - mx) : 0.f;
    sum += e[j];
  }
  #pragma unroll
  for (int s = 1; s < 64; s <<= 1) sum += __shfl_xor(sum, s, 64);
  float inv = 1.f / sum;
  #pragma unroll
  for (int j = 0; j < 8; ++j)
    g[b * T + j * 64 + lane] = e[j] * inv;
}

// ---------------------------------------------------------------- K4: AGRU scan, VGPR-resident weights
// 512 threads: gate 0 (0..255) computes r_i; gate 1 (256..511) computes h_i.
// Weights: 128 f16x2 per thread (own output row). h broadcast via f16 LDS array.
__global__ __launch_bounds__(512, 2) void k_scan_v2(
    const float* __restrict__ Fr, const float* __restrict__ Fg, const float* __restrict__ g,
    const int* __restrict__ num_facts, const float* __restrict__ Ur_w,
    const float* __restrict__ Ug_w, const float* __restrict__ Ug_b,
    const float* __restrict__ m_old, float* __restrict__ c_out)
{
  const int b = blockIdx.x;
  const int tid = threadIdx.x;
  const int gate = tid >> 8;
  const int i = tid & 255;
  const int nf = num_facts[b];

  __shared__ __align__(16) f16 h_h[256];
  __shared__ float r_sh[256];

  // pack this thread's weight row into VGPRs as f16x2
  const float* __restrict__ Wrow = (gate ? Ug_w : Ur_w) + (int64_t)i * 256;
  f16x2 w[128];
  #pragma unroll
  for (int k = 0; k < 128; ++k) {
    float2 f2 = *(const float2*)(Wrow + 2 * k);
    f16x2 p; p[0] = (f16)f2.x; p[1] = (f16)f2.y;
    w[k] = p;
  }
  const float ugb = gate ? Ug_b[i] : 0.f;
  float h = m_old[b * 256 + i];
  if (gate == 1) h_h[i] = (f16)h;
  __syncthreads();

  const float* __restrict__ Fx = (gate ? Fg : Fr) + (int64_t)(b * T) * D + i;
  const float* __restrict__ gp = g + b * T;
  float fx = Fx[0];
  float gt = gp[0];

  for (int t = 0; t < nf; ++t) {
    // prefetch next step's inputs (used only after the dot chain -> latency hidden)
    float fx_n = 0.f, gt_n = 0.f;
    if (t + 1 < nf) {
      fx_n = Fx[(int64_t)(t + 1) * D];
      gt_n = gp[t + 1];
    }

    // dot(W_row, h) over 256 elements: 32 x 16B LDS broadcast reads, 128 dot2
    float a0 = 0.f, a1 = 0.f, a2 = 0.f, a3 = 0.f;
    const u32x4* __restrict__ hp = (const u32x4*)h_h;
    #pragma unroll
    for (int c = 0; c < 32; ++c) {
      u32x4 hv = hp[c];
      a0 = dot2f(as_h2(hv.x), w[c * 4 + 0], a0);
      a1 = dot2f(as_h2(hv.y), w[c * 4 + 1], a1);
      a2 = dot2f(as_h2(hv.z), w[c * 4 + 2], a2);
      a3 = dot2f(as_h2(hv.w), w[c * 4 + 3], a3);
    }
    float dotv = (a0 + a1) + (a2 + a3);

    if (gate == 0)
      r_sh[i] = 1.f / (1.f + __expf(-(fx + dotv)));   // fx = Fr (has Ur_b folded)
    __syncthreads();
    if (gate == 1) {
      float ht = tanhf(fx + r_sh[i] * (dotv + ugb));  // fx = Fg
      h = gt * ht + (1.f - gt) * h;
      h_h[i] = (f16)h;
    }
    fx = fx_n;
    gt = gt_n;
    __syncthreads();
  }
  if (gate == 1) c_out[b * 256 + i] = h;
}

// ---------------------------------------------------------------- K5: m_new = relu(cat @ Wt^T + bt)
__global__ __launch_bounds__(256) void k_final2(
    const float* __restrict__ m_old, const float* __restrict__ c_ws,
    const float* __restrict__ queries, const float* __restrict__ Wt_w,
    const float* __restrict__ Wt_b, float* __restrict__ out)
{
  const int b = blockIdx.x;
  const int tid = threadIdx.x;
  __shared__ __align__(16) float cat_s[768];
  for (int e = tid; e < 768; e += 256) {
    float v = (e < 256) ? m_old[b * 256 + e]
            : (e < 512) ? c_ws[b * 256 + (e - 256)]
                        : queries[b * 256 + (e - 512)];
    cat_s[e] = v;
  }
  __syncthreads();
  const float* wrow = Wt_w + (int64_t)tid * 768;
  float acc = 0.f;
  #pragma unroll 8
  for (int k = 0; k < 768; k += 4) {
    float4 w = *(const float4*)(wrow + k);
    float4 c4 = *(const float4*)(cat_s + k);
    acc += w.x * c4.x + w.y * c4.y + w.z * c4.z + w.w * c4.w;
  }
  out[b * 256 + tid] = fmaxf(acc + Wt_b[tid], 0.f);
}

// ----------------------------------------------------------------
extern "C" void kernel_launch(void* const* d_in, const int* in_sizes, int n_in,
                              void* d_out, int out_size, void* d_ws, size_t ws_size,
                              hipStream_t stream)
{
  const float* queries   = (const float*)d_in[0];
  const float* facts     = (const float*)d_in[1];
  const int*   num_facts = (const int*)d_in[2];
  const float* m_old     = (const float*)d_in[3];
  const float* W1_w = (const float*)d_in[4];
  const float* W1_b = (const float*)d_in[5];
  const float* W2_w = (const float*)d_in[6];
  const float* W2_b = (const float*)d_in[7];
  const float* Wr_w = (const float*)d_in[8];
  const float* Ur_w = (const float*)d_in[9];
  const float* Ur_b = (const float*)d_in[10];
  const float* Wg_w = (const float*)d_in[11];
  const float* Ug_w = (const float*)d_in[12];
  const float* Ug_b = (const float*)d_in[13];
  const float* Wt_w = (const float*)d_in[14];
  const float* Wt_b = (const float*)d_in[15];
  float* out = (float*)d_out;

  char* p = (char*)d_ws;
  auto alloc = [&](size_t bytes) { char* r = p; p += (bytes + 255) & ~(size_t)255; return r; };
  float* W1t  = (float*)alloc((size_t)262144 * 4);
  float* Wrt  = (float*)alloc((size_t)65536 * 4);
  float* Wgt  = (float*)alloc((size_t)65536 * 4);
  float* Zlog = (float*)alloc((size_t)B * T * 4);
  float* g    = (float*)alloc((size_t)B * T * 4);
  float* Fr   = (float*)alloc((size_t)B * T * D * 4);
  float* Fg   = (float*)alloc((size_t)B * T * D * 4);
  float* c_ws = (float*)alloc((size_t)B * D * 4);

  k_prep<<<dim3(512), dim3(256), 0, stream>>>(W1_w, Wr_w, Wg_w, W1t, Wrt, Wgt);
  k_attn_f32<<<dim3(16, 64), dim3(256), 0, stream>>>(facts, queries, m_old, W1t, W1_b, W2_w, W2_b, Zlog);
  k_factproj_f32<<<dim3(16, 64), dim3(256), 0, stream>>>(facts, Wrt, Wgt, Ur_b, Fr, Fg);
  k_softmax2<<<dim3(64), dim3(64), 0, stream>>>(Zlog, num_facts, g);
  k_scan_v2<<<dim3(64), dim3(512), 0, stream>>>(Fr, Fg, g, num_facts, Ur_w, Ug_w, Ug_b, m_old, c_ws);
  k_final2<<<dim3(64), dim3(256), 0, stream>>>(m_old, c_ws, queries, Wt_w, Wt_b, out);
}

// Round 5
// 773.990 us; speedup vs baseline: 10.1121x; 1.3237x over previous
//
#include <hip/hip_runtime.h>
#include <hip/hip_fp16.h>
#include <stdint.h>

#define B 64
#define T 512
#define D 256

typedef _Float16 f16;
typedef __attribute__((ext_vector_type(8))) _Float16 f16x8;
typedef __attribute__((ext_vector_type(2))) _Float16 f16x2;
typedef __attribute__((ext_vector_type(4))) float f32x4;
typedef __attribute__((ext_vector_type(4))) unsigned int u32x4;

static __device__ __forceinline__ float dot2f(f16x2 a, f16x2 b, float c) {
  return __builtin_amdgcn_fdot2(a, b, c, false);
}
static __device__ __forceinline__ f16x2 as_h2(unsigned int u) {
  return __builtin_bit_cast(f16x2, u);
}

// ---------------------------------------------------------------- K0: f32->f16 converts
__global__ void k_convert(const float* __restrict__ W1, const float* __restrict__ Wr,
                          const float* __restrict__ Wg, const float* __restrict__ facts,
                          f16* __restrict__ W1h, f16* __restrict__ Wrh,
                          f16* __restrict__ Wgh, f16* __restrict__ Fh)
{
  const int64_t n1 = 256 * 1024, n2 = 65536, n3 = 65536, n4 = (int64_t)B * T * D;
  int64_t stride = (int64_t)gridDim.x * blockDim.x;
  for (int64_t i = (int64_t)blockIdx.x * blockDim.x + threadIdx.x; i < n1 + n2 + n3 + n4; i += stride) {
    if (i < n1)                W1h[i] = (f16)W1[i];
    else if (i < n1 + n2)      Wrh[i - n1] = (f16)Wr[i - n1];
    else if (i < n1 + n2 + n3) Wgh[i - n1 - n2] = (f16)Wg[i - n1 - n2];
    else                       Fh[i - n1 - n2 - n3] = (f16)facts[i - n1 - n2 - n3];
  }
}

// ---------------------------------------------------------------- K1: attention logits (MFMA f16)
// Z[b][t] = W2 . tanh(W1 @ z(b,t) + b1) + b2, z = [f*q, f*m, |f-q|, |f-m|] (K=1024)
__global__ __launch_bounds__(256, 2) void k_attn(
    const float* __restrict__ facts, const float* __restrict__ queries,
    const float* __restrict__ m_old, const f16* __restrict__ W1h,
    const float* __restrict__ W1_b, const float* __restrict__ W2_w,
    const float* __restrict__ W2_b, float* __restrict__ Zlog)
{
  const int b = blockIdx.y;
  const int t0 = blockIdx.x * 32;
  const int tid = threadIdx.x;
  const int lane = tid & 63;
  const int wave = tid >> 6;
  const int lr = lane & 15;
  const int lg = lane >> 4;

  __shared__ float q_s[D], m_s[D];
  __shared__ __align__(16) char zbuf[32 * 2048];   // 32 rows x 1024 f16 (XOR-swizzled)
  __shared__ float part[4][32];

  q_s[tid] = queries[b * D + tid];
  m_s[tid] = m_old[b * D + tid];
  __syncthreads();

  for (int e = tid; e < 32 * 128; e += 256) {
    int t = e >> 7;
    int j2 = e & 127;
    int j = j2 * 2;
    const float2 f2 = *(const float2*)(facts + ((int64_t)(b * T) + t0 + t) * D + j);
    float q0 = q_s[j], q1 = q_s[j + 1], mm0 = m_s[j], mm1 = m_s[j + 1];
    f16x2 z0; z0[0] = (f16)(f2.x * q0);        z0[1] = (f16)(f2.y * q1);
    f16x2 z1; z1[0] = (f16)(f2.x * mm0);       z1[1] = (f16)(f2.y * mm1);
    f16x2 z2; z2[0] = (f16)fabsf(f2.x - q0);   z2[1] = (f16)fabsf(f2.y - q1);
    f16x2 z3; z3[0] = (f16)fabsf(f2.x - mm0);  z3[1] = (f16)fabsf(f2.y - mm1);
    int xr = (t & 7) << 4;
    int base = t * 2048;
    *(f16x2*)(zbuf + ((base + (0 * 128 + j2) * 4) ^ xr)) = z0;
    *(f16x2*)(zbuf + ((base + (1 * 128 + j2) * 4) ^ xr)) = z1;
    *(f16x2*)(zbuf + ((base + (2 * 128 + j2) * 4) ^ xr)) = z2;
    *(f16x2*)(zbuf + ((base + (3 * 128 + j2) * 4) ^ xr)) = z3;
  }
  __syncthreads();

  const int n0 = wave * 64;
  f32x4 acc[2][4];
  #pragma unroll
  for (int i = 0; i < 2; ++i)
    #pragma unroll
    for (int j = 0; j < 4; ++j) acc[i][j] = (f32x4){0.f, 0.f, 0.f, 0.f};

  #pragma unroll 2
  for (int ks = 0; ks < 32; ++ks) {
    f16x8 af[2];
    #pragma unroll
    for (int mt = 0; mt < 2; ++mt) {
      int row = mt * 16 + lr;
      int byte = (row * 2048 + ks * 64 + lg * 16) ^ ((row & 7) << 4);
      af[mt] = *(const f16x8*)(zbuf + byte);
    }
    #pragma unroll
    for (int nt = 0; nt < 4; ++nt) {
      int a = n0 + nt * 16 + lr;
      f16x8 bf = *(const f16x8*)(W1h + (int64_t)a * 1024 + ks * 32 + lg * 8);
      acc[0][nt] = __builtin_amdgcn_mfma_f32_16x16x32_f16(af[0], bf, acc[0][nt], 0, 0, 0);
      acc[1][nt] = __builtin_amdgcn_mfma_f32_16x16x32_f16(af[1], bf, acc[1][nt], 0, 0, 0);
    }
  }

  float pr[2][4] = {{0.f, 0.f, 0.f, 0.f}, {0.f, 0.f, 0.f, 0.f}};
  #pragma unroll
  for (int nt = 0; nt < 4; ++nt) {
    int a = n0 + nt * 16 + lr;
    float b1 = W1_b[a];
    float w2 = W2_w[a];
    #pragma unroll
    for (int mt = 0; mt < 2; ++mt)
      #pragma unroll
      for (int r = 0; r < 4; ++r)
        pr[mt][r] += tanhf(acc[mt][nt][r] + b1) * w2;
  }
  #pragma unroll
  for (int mt = 0; mt < 2; ++mt)
    #pragma unroll
    for (int r = 0; r < 4; ++r) {
      float v = pr[mt][r];
      v += __shfl_xor(v, 1, 64);
      v += __shfl_xor(v, 2, 64);
      v += __shfl_xor(v, 4, 64);
      v += __shfl_xor(v, 8, 64);
      pr[mt][r] = v;
    }
  if ((lane & 15) == 0) {
    #pragma unroll
    for (int mt = 0; mt < 2; ++mt)
      #pragma unroll
      for (int r = 0; r < 4; ++r)
        part[wave][mt * 16 + lg * 4 + r] = pr[mt][r];
  }
  __syncthreads();
  if (tid < 32)
    Zlog[b * T + t0 + tid] = part[0][tid] + part[1][tid] + part[2][tid] + part[3][tid] + W2_b[0];
}

// ---------------------------------------------------------------- K2: fact projections (MFMA f16, f32 out)
// Fr = facts@Wr^T + Ur_b ; Fg = facts@Wg^T
__global__ __launch_bounds__(256, 2) void k_factproj(
    const f16* __restrict__ Fh, const f16* __restrict__ Wrh, const f16* __restrict__ Wgh,
    const float* __restrict__ Ur_b, float* __restrict__ Fr, float* __restrict__ Fg)
{
  const int b = blockIdx.y;
  const int t0 = blockIdx.x * 64;
  const int tid = threadIdx.x;
  const int lane = tid & 63;
  const int wave = tid >> 6;
  const int lr = lane & 15;
  const int lg = lane >> 4;

  __shared__ __align__(16) char albuf[64 * 512];   // 64 rows x 256 f16, swizzled

  for (int c = tid; c < 64 * 32; c += 256) {
    int row = c >> 5;
    int kc = c & 31;
    f16x8 v = *(const f16x8*)(Fh + ((int64_t)(b * T) + t0 + row) * D + kc * 8);
    int byte = (row * 512 + kc * 16) ^ ((row & 7) << 4);
    *(f16x8*)(albuf + byte) = v;
  }
  __syncthreads();

  f32x4 accr[16], accg[16];
  #pragma unroll
  for (int i = 0; i < 16; ++i) { accr[i] = (f32x4){0.f,0.f,0.f,0.f}; accg[i] = (f32x4){0.f,0.f,0.f,0.f}; }

  const int arow = wave * 16 + lr;
  #pragma unroll 2
  for (int ks = 0; ks < 8; ++ks) {
    int byte = (arow * 512 + ks * 64 + lg * 16) ^ ((arow & 7) << 4);
    f16x8 af = *(const f16x8*)(albuf + byte);
    #pragma unroll
    for (int nt = 0; nt < 16; ++nt) {
      int a = nt * 16 + lr;
      f16x8 br = *(const f16x8*)(Wrh + a * 256 + ks * 32 + lg * 8);
      f16x8 bg = *(const f16x8*)(Wgh + a * 256 + ks * 32 + lg * 8);
      accr[nt] = __builtin_amdgcn_mfma_f32_16x16x32_f16(af, br, accr[nt], 0, 0, 0);
      accg[nt] = __builtin_amdgcn_mfma_f32_16x16x32_f16(af, bg, accg[nt], 0, 0, 0);
    }
  }

  #pragma unroll
  for (int nt = 0; nt < 16; ++nt) {
    int col = nt * 16 + lr;
    float urb = Ur_b[col];
    #pragma unroll
    for (int r = 0; r < 4; ++r) {
      int t = t0 + wave * 16 + lg * 4 + r;
      int64_t off = ((int64_t)(b * T) + t) * D + col;
      Fr[off] = accr[nt][r] + urb;
      Fg[off] = accg[nt][r];
    }
  }
}

// ---------------------------------------------------------------- K3: masked softmax, 1 wave per batch
__global__ void k_softmax2(const float* __restrict__ Zlog, const int* __restrict__ num_facts,
                           float* __restrict__ g)
{
  const int b = blockIdx.x;
  const int lane = threadIdx.x;       // 64 threads
  const int nf = num_facts[b];
  float v[8];
  float mx = -INFINITY;
  #pragma unroll
  for (int j = 0; j < 8; ++j) {
    int t = j * 64 + lane;
    float z = Zlog[b * T + t];
    v[j] = (t < nf) ? z : -INFINITY;
    mx = fmaxf(mx, v[j]);
  }
  #pragma unroll
  for (int s = 1; s < 64; s <<= 1) mx = fmaxf(mx, __shfl_xor(mx, s, 64));
  float e[8];
  float sum = 0.f;
  #pragma unroll
  for (int j = 0; j < 8; ++j) {
    int t = j * 64 + lane;
    e[j] = (t < nf) ? __expf(v[j] - mx) : 0.f;
    sum += e[j];
  }
  #pragma unroll
  for (int s = 1; s < 64; s <<= 1) sum += __shfl_xor(sum, s, 64);
  float inv = 1.f / sum;
  #pragma unroll
  for (int j = 0; j < 8; ++j)
    g[b * T + j * 64 + lane] = e[j] * inv;
}

// ---------------------------------------------------------------- K4: AGRU scan v3
// 512 threads, fused gates. lane=(row_lo, k-half): thread owns output row
// row = wave*32 + (lane&31), k-slice = (lane>>5)*128..+127 (128 f16 weights/gate).
// dots: 64+64 dot2 on distributed h; combine halves with one shfl_xor(32).
// Ping-pong h buffer -> single barrier per step.
__global__ __launch_bounds__(512, 2) void k_scan_v3(
    const float* __restrict__ Fr, const float* __restrict__ Fg, const float* __restrict__ g,
    const int* __restrict__ num_facts, const float* __restrict__ Ur_w,
    const float* __restrict__ Ug_w, const float* __restrict__ Ug_b,
    const float* __restrict__ m_old, float* __restrict__ c_out)
{
  const int b = blockIdx.x;
  const int tid = threadIdx.x;
  const int row = ((tid >> 6) << 5) + (tid & 31);
  const int kgh = (tid >> 5) & 1;
  const int nf = num_facts[b];

  __shared__ __align__(16) f16 hbuf[2][256];

  // pack this thread's k-half of both weight rows into VGPRs
  const float* __restrict__ urow = Ur_w + (int64_t)row * 256 + kgh * 128;
  const float* __restrict__ grow = Ug_w + (int64_t)row * 256 + kgh * 128;
  f16x2 wR[64], wG[64];
  #pragma unroll
  for (int j = 0; j < 64; ++j) {
    float2 a = *(const float2*)(urow + 2 * j);
    float2 c = *(const float2*)(grow + 2 * j);
    f16x2 pa; pa[0] = (f16)a.x; pa[1] = (f16)a.y; wR[j] = pa;
    f16x2 pc; pc[0] = (f16)c.x; pc[1] = (f16)c.y; wG[j] = pc;
  }
  const float ugb = Ug_b[row];
  float h = m_old[b * 256 + row];
  if (kgh == 0) hbuf[0][row] = (f16)h;
  __syncthreads();

  const float* __restrict__ FrP = Fr + (int64_t)(b * T) * D + row;
  const float* __restrict__ FgP = Fg + (int64_t)(b * T) * D + row;
  const float* __restrict__ gP  = g + b * T;
  float fr = FrP[0], fg = FgP[0], gt = gP[0];

  const f16* hc = hbuf[0];
  f16* hn = hbuf[1];

  for (int t = 0; t < nf; ++t) {
    // prefetch next step's inputs (consumed after the dot chain)
    float fr_n = 0.f, fg_n = 0.f, gt_n = 0.f;
    if (t + 1 < nf) {
      fr_n = FrP[(int64_t)(t + 1) * D];
      fg_n = FgP[(int64_t)(t + 1) * D];
      gt_n = gP[t + 1];
    }

    // partial dots over this thread's 128-element k-slice
    const u32x4* __restrict__ hp = (const u32x4*)(hc + kgh * 128);
    float r0 = 0.f, r1 = 0.f, r2 = 0.f, r3 = 0.f;
    float q0 = 0.f, q1 = 0.f, q2 = 0.f, q3 = 0.f;
    #pragma unroll
    for (int c = 0; c < 16; ++c) {
      u32x4 hv = hp[c];
      f16x2 h0 = as_h2(hv.x), h1 = as_h2(hv.y), h2 = as_h2(hv.z), h3 = as_h2(hv.w);
      r0 = dot2f(h0, wR[c * 4 + 0], r0);
      r1 = dot2f(h1, wR[c * 4 + 1], r1);
      r2 = dot2f(h2, wR[c * 4 + 2], r2);
      r3 = dot2f(h3, wR[c * 4 + 3], r3);
      q0 = dot2f(h0, wG[c * 4 + 0], q0);
      q1 = dot2f(h1, wG[c * 4 + 1], q1);
      q2 = dot2f(h2, wG[c * 4 + 2], q2);
      q3 = dot2f(h3, wG[c * 4 + 3], q3);
    }
    float dR = (r0 + r1) + (r2 + r3);
    float dG = (q0 + q1) + (q2 + q3);
    dR += __shfl_xor(dR, 32, 64);   // combine the two k-halves (lane ^ 32 = same row)
    dG += __shfl_xor(dG, 32, 64);

    float rr = 1.f / (1.f + __expf(-(fr + dR)));   // fr has Ur_b folded
    float ht = tanhf(fg + rr * (dG + ugb));
    h = gt * ht + (1.f - gt) * h;
    if (kgh == 0) hn[row] = (f16)h;

    fr = fr_n; fg = fg_n; gt = gt_n;
    const f16* tmp = hc; hc = hn; hn = (f16*)tmp;
    __syncthreads();
  }
  if (kgh == 0) c_out[b * 256 + row] = h;
}

// ---------------------------------------------------------------- K5: m_new = relu(cat @ Wt^T + bt)
__global__ __launch_bounds__(256) void k_final2(
    const float* __restrict__ m_old, const float* __restrict__ c_ws,
    const float* __restrict__ queries, const float* __restrict__ Wt_w,
    const float* __restrict__ Wt_b, float* __restrict__ out)
{
  const int b = blockIdx.x;
  const int tid = threadIdx.x;
  __shared__ __align__(16) float cat_s[768];
  for (int e = tid; e < 768; e += 256) {
    float v = (e < 256) ? m_old[b * 256 + e]
            : (e < 512) ? c_ws[b * 256 + (e - 256)]
                        : queries[b * 256 + (e - 512)];
    cat_s[e] = v;
  }
  __syncthreads();
  const float* wrow = Wt_w + (int64_t)tid * 768;
  float acc = 0.f;
  #pragma unroll 8
  for (int k = 0; k < 768; k += 4) {
    float4 w = *(const float4*)(wrow + k);
    float4 c4 = *(const float4*)(cat_s + k);
    acc += w.x * c4.x + w.y * c4.y + w.z * c4.z + w.w * c4.w;
  }
  out[b * 256 + tid] = fmaxf(acc + Wt_b[tid], 0.f);
}

// ----------------------------------------------------------------
extern "C" void kernel_launch(void* const* d_in, const int* in_sizes, int n_in,
                              void* d_out, int out_size, void* d_ws, size_t ws_size,
                              hipStream_t stream)
{
  const float* queries   = (const float*)d_in[0];
  const float* facts     = (const float*)d_in[1];
  const int*   num_facts = (const int*)d_in[2];
  const float* m_old     = (const float*)d_in[3];
  const float* W1_w = (const float*)d_in[4];
  const float* W1_b = (const float*)d_in[5];
  const float* W2_w = (const float*)d_in[6];
  const float* W2_b = (const float*)d_in[7];
  const float* Wr_w = (const float*)d_in[8];
  const float* Ur_w = (const float*)d_in[9];
  const float* Ur_b = (const float*)d_in[10];
  const float* Wg_w = (const float*)d_in[11];
  const float* Ug_w = (const float*)d_in[12];
  const float* Ug_b = (const float*)d_in[13];
  const float* Wt_w = (const float*)d_in[14];
  const float* Wt_b = (const float*)d_in[15];
  float* out = (float*)d_out;

  char* p = (char*)d_ws;
  auto alloc = [&](size_t bytes) { char* r = p; p += (bytes + 255) & ~(size_t)255; return r; };
  f16*   W1h  = (f16*)alloc((size_t)256 * 1024 * 2);
  f16*   Wrh  = (f16*)alloc((size_t)65536 * 2);
  f16*   Wgh  = (f16*)alloc((size_t)65536 * 2);
  f16*   Fh   = (f16*)alloc((size_t)B * T * D * 2);
  float* Zlog = (float*)alloc((size_t)B * T * 4);
  float* g    = (float*)alloc((size_t)B * T * 4);
  float* Fr   = (float*)alloc((size_t)B * T * D * 4);
  float* Fg   = (float*)alloc((size_t)B * T * D * 4);
  float* c_ws = (float*)alloc((size_t)B * D * 4);

  k_convert<<<dim3(2048), dim3(256), 0, stream>>>(W1_w, Wr_w, Wg_w, facts, W1h, Wrh, Wgh, Fh);
  k_attn<<<dim3(16, 64), dim3(256), 0, stream>>>(facts, queries, m_old, W1h, W1_b, W2_w, W2_b, Zlog);
  k_factproj<<<dim3(8, 64), dim3(256), 0, stream>>>(Fh, Wrh, Wgh, Ur_b, Fr, Fg);
  k_softmax2<<<dim3(64), dim3(64), 0, stream>>>(Zlog, num_facts, g);
  k_scan_v3<<<dim3(64), dim3(512), 0, stream>>>(Fr, Fg, g, num_facts, Ur_w, Ug_w, Ug_b, m_old, c_ws);
  k_final2<<<dim3(64), dim3(256), 0, stream>>>(m_old, c_ws, queries, Wt_w, Wt_b, out);
}